// Round 5
// baseline (29.672 us; speedup 1.0000x reference)
//
#include <hip/hip_runtime.h>

#define D 64
#define K 50
#define GROUPS 8              // 8 groups of 8 lanes; each group reads one neighbor row/iter
#define KPAD 56               // ceil(50/8)*8
#define ITERS (KPAD / GROUPS) // 7
#define ROWS_PER_BLOCK 4      // one wave per output row
#define THREADS 256

// ---------- prologue: emb fp32 -> bf16 (RNE) into ws; rtab[u] = deg>0 ? rsqrt(deg) : 0
__global__ __launch_bounds__(THREADS)
void prep_kernel(const float* __restrict__ emb, const float* __restrict__ deg,
                 unsigned* __restrict__ emb16, float* __restrict__ rtab,
                 int npack4, int nuser)
{
    const int p = blockIdx.x * THREADS + threadIdx.x;
    if (p < npack4) {
        const float4 f = ((const float4*)emb)[p];
        unsigned a = __float_as_uint(f.x), b = __float_as_uint(f.y);
        unsigned c = __float_as_uint(f.z), d = __float_as_uint(f.w);
        a = (a + 0x7FFFu + ((a >> 16) & 1u)) >> 16;   // RNE bf16
        b = (b + 0x7FFFu + ((b >> 16) & 1u)) >> 16;
        c = (c + 0x7FFFu + ((c >> 16) & 1u)) >> 16;
        d = (d + 0x7FFFu + ((d >> 16) & 1u)) >> 16;
        ((uint2*)emb16)[p] = make_uint2(a | (b << 16), c | (d << 16));
    }
    if (p < nuser) {
        const float n = deg[p];
        rtab[p] = (n > 0.0f) ? rsqrtf(n) : 0.0f;
    }
}

// ---------- main: bf16 gather; 8 lanes x 16B per neighbor row -> 1024B/instr, 8 rows/instr
__global__ __launch_bounds__(THREADS)
void social_agg_bf16(const int* __restrict__ nodes,
                     const int* __restrict__ u_u,
                     const float* __restrict__ rtab,
                     const unsigned* __restrict__ emb16,
                     float* __restrict__ out,
                     int batch)
{
    __shared__ uint2 nw[ROWS_PER_BLOCK][KPAD];   // x = neighbor id, y = bitcast(w)
    const int base = blockIdx.x * ROWS_PER_BLOCK;

    const int p = threadIdx.x;
    if (p < ROWS_PER_BLOCK * KPAD) {
        const int r   = p / KPAD;
        const int k   = p - r * KPAD;
        const int row = base + r;
        int nb = 0; float w = 0.0f;
        if (row < batch && k < K) {
            const int node = nodes[row];
            nb = u_u[node * K + k];
            w  = rtab[node] * rtab[nb];          // 0 whenever either degree is 0
        }
        nw[r][k] = make_uint2((unsigned)nb, __float_as_uint(w));
    }
    __syncthreads();

    const int wave = threadIdx.x >> 6;
    const int lane = threadIdx.x & 63;
    const int g    = lane >> 3;                  // K-group 0..7
    const int sub  = lane & 7;                   // 16B slice of the 128B row
    const int row  = base + wave;

    float acc[8] = {0.f, 0.f, 0.f, 0.f, 0.f, 0.f, 0.f, 0.f};
    #pragma unroll
    for (int i = 0; i < ITERS; ++i) {
        const uint2 e  = nw[wave][i * GROUPS + g];
        const float wk = __uint_as_float(e.y);
        const uint4 v  = *(const uint4*)(emb16 + (size_t)e.x * (D / 2) + sub * 4);
        acc[0] += wk * __uint_as_float(v.x << 16);
        acc[1] += wk * __uint_as_float(v.x & 0xFFFF0000u);
        acc[2] += wk * __uint_as_float(v.y << 16);
        acc[3] += wk * __uint_as_float(v.y & 0xFFFF0000u);
        acc[4] += wk * __uint_as_float(v.z << 16);
        acc[5] += wk * __uint_as_float(v.z & 0xFFFF0000u);
        acc[6] += wk * __uint_as_float(v.w << 16);
        acc[7] += wk * __uint_as_float(v.w & 0xFFFF0000u);
    }

    // Reduce the 8 K-groups (lanes sub, 8+sub, ..., 56+sub hold partials).
    #pragma unroll
    for (int off = 8; off <= 32; off <<= 1) {
        #pragma unroll
        for (int j = 0; j < 8; ++j) acc[j] += __shfl_xor(acc[j], off);
    }

    if (row < batch && g == 0) {
        float* o = out + (size_t)row * D + sub * 8;
        *(float4*)(o)     = make_float4(acc[0], acc[1], acc[2], acc[3]);
        *(float4*)(o + 4) = make_float4(acc[4], acc[5], acc[6], acc[7]);
    }
}

// ---------- fallback (fp32 path) if workspace is too small
__global__ __launch_bounds__(THREADS)
void social_agg_f32(const int* __restrict__ nodes,
                    const int* __restrict__ u_u,
                    const float* __restrict__ u_u_l,
                    const float* __restrict__ emb,
                    float* __restrict__ out,
                    int batch)
{
    __shared__ uint2 nw[ROWS_PER_BLOCK][KPAD];
    const int base = blockIdx.x * ROWS_PER_BLOCK;
    const int p = threadIdx.x;
    if (p < ROWS_PER_BLOCK * KPAD) {
        const int r = p / KPAD, k = p - r * KPAD, row = base + r;
        int nb = 0; float w = 0.0f;
        if (row < batch && k < K) {
            const int node = nodes[row];
            const float Na = u_u_l[node];
            nb = u_u[node * K + k];
            const float prod = Na * u_u_l[nb];
            w = (prod > 0.0f) ? rsqrtf(prod) : 0.0f;
        }
        nw[r][k] = make_uint2((unsigned)nb, __float_as_uint(w));
    }
    __syncthreads();
    const int wave = threadIdx.x >> 6, lane = threadIdx.x & 63;
    const int kk = lane >> 4, sub = lane & 15, row = base + wave;
    float4 acc = make_float4(0.f, 0.f, 0.f, 0.f);
    #pragma unroll
    for (int i = 0; i < 13; ++i) {
        const int k = i * 4 + kk;
        const uint2 e = nw[wave][k < KPAD ? k : 0];
        const float wk = (k < KPAD) ? __uint_as_float(e.y) : 0.0f;
        const float4 v = *(const float4*)(emb + (size_t)e.x * D + sub * 4);
        acc.x += wk * v.x; acc.y += wk * v.y; acc.z += wk * v.z; acc.w += wk * v.w;
    }
    #pragma unroll
    for (int off = 16; off <= 32; off <<= 1) {
        acc.x += __shfl_xor(acc.x, off);
        acc.y += __shfl_xor(acc.y, off);
        acc.z += __shfl_xor(acc.z, off);
        acc.w += __shfl_xor(acc.w, off);
    }
    if (row < batch && kk == 0)
        *(float4*)(out + (size_t)row * D + sub * 4) = acc;
}

extern "C" void kernel_launch(void* const* d_in, const int* in_sizes, int n_in,
                              void* d_out, int out_size, void* d_ws, size_t ws_size,
                              hipStream_t stream) {
    const int*   nodes = (const int*)d_in[0];
    const int*   u_u   = (const int*)d_in[1];
    const float* u_u_l = (const float*)d_in[2];
    const float* emb   = (const float*)d_in[3];
    float*       out   = (float*)d_out;

    const int batch  = in_sizes[0];
    const int nuser  = in_sizes[1] / K;                  // N_USERS
    const int blocks = (batch + ROWS_PER_BLOCK - 1) / ROWS_PER_BLOCK;

    const size_t emb16_bytes = (size_t)nuser * D * 2;    // bf16 table
    const size_t rtab_bytes  = (size_t)nuser * 4;
    if (ws_size >= emb16_bytes + rtab_bytes) {
        unsigned* emb16 = (unsigned*)d_ws;
        float*    rtab  = (float*)((char*)d_ws + emb16_bytes);
        const int npack4 = nuser * D / 4;                // float4 packs
        const int pblocks = (npack4 + THREADS - 1) / THREADS;
        prep_kernel<<<pblocks, THREADS, 0, stream>>>(emb, u_u_l, emb16, rtab,
                                                     npack4, nuser);
        social_agg_bf16<<<blocks, THREADS, 0, stream>>>(nodes, u_u, rtab, emb16,
                                                        out, batch);
    } else {
        social_agg_f32<<<blocks, THREADS, 0, stream>>>(nodes, u_u, u_u_l, emb,
                                                       out, batch);
    }
}

// Round 6
// 29.518 us; speedup vs baseline: 1.0052x; 1.0052x over previous
//
#include <hip/hip_runtime.h>

#define D 64
#define K 50
#define GROUPS 8              // 8 groups x 8 lanes; each group reads one neighbor row/iter
#define KPAD 56               // ceil(50/8)*8
#define ITERS (KPAD / GROUPS) // 7
#define ROWS_PER_BLOCK 4      // one wave per output row
#define THREADS 256

// ---------- prologue: per-row int8 quantization of emb + rtab = rsqrt(deg)
// 16 lanes per row, 4 dims per lane. emb8 row = 64 B (16 u32), scale[row] = rowmax/127.
__global__ __launch_bounds__(THREADS)
void prep_q8(const float* __restrict__ emb, const float* __restrict__ deg,
             unsigned* __restrict__ emb8, float* __restrict__ scale,
             float* __restrict__ rtab, int nuser)
{
    const int tid = blockIdx.x * THREADS + threadIdx.x;
    const int row = tid >> 4;
    const int sub = tid & 15;

    if (row < nuser) {
        const float4 f = ((const float4*)emb)[row * 16 + sub];
        float m = fmaxf(fmaxf(fabsf(f.x), fabsf(f.y)), fmaxf(fabsf(f.z), fabsf(f.w)));
        #pragma unroll
        for (int off = 1; off < 16; off <<= 1)
            m = fmaxf(m, __shfl_xor(m, off));            // rowmax across the 16-lane group
        const float inv = (m > 0.0f) ? 127.0f / m : 0.0f;
        const int q0 = (int)rintf(f.x * inv);
        const int q1 = (int)rintf(f.y * inv);
        const int q2 = (int)rintf(f.z * inv);
        const int q3 = (int)rintf(f.w * inv);
        const unsigned pk = (q0 & 0xFF) | ((q1 & 0xFF) << 8) |
                            ((q2 & 0xFF) << 16) | ((unsigned)(q3 & 0xFF) << 24);
        emb8[row * 16 + sub] = pk;                       // 64 B per group, coalesced
        if (sub == 0) scale[row] = m * (1.0f / 127.0f);
    }
    if (tid < nuser) {
        const float n = deg[tid];
        rtab[tid] = (n > 0.0f) ? rsqrtf(n) : 0.0f;
    }
}

__device__ __forceinline__ float sb(unsigned v, int byte) {
    return (float)((int)(v << (24 - 8 * byte)) >> 24);   // sign-extend byte -> float
}

// ---------- main: int8 gather; 8 lanes x 8 B per 64 B neighbor row
__global__ __launch_bounds__(THREADS)
void social_agg_q8(const int* __restrict__ nodes,
                   const int* __restrict__ u_u,
                   const float* __restrict__ rtab,
                   const float* __restrict__ scale,
                   const unsigned* __restrict__ emb8,
                   float* __restrict__ out,
                   int batch)
{
    __shared__ uint2 nw[ROWS_PER_BLOCK][KPAD];   // x = neighbor id, y = bitcast(w*scale)
    const int base = blockIdx.x * ROWS_PER_BLOCK;

    const int p = threadIdx.x;
    if (p < ROWS_PER_BLOCK * KPAD) {
        const int r   = p / KPAD;
        const int k   = p - r * KPAD;
        const int row = base + r;
        int nb = 0; float w = 0.0f;
        if (row < batch && k < K) {
            const int node = nodes[row];
            nb = u_u[node * K + k];
            w  = rtab[node] * rtab[nb] * scale[nb];   // dequant scale folded in; 0 if deg==0
        }
        nw[r][k] = make_uint2((unsigned)nb, __float_as_uint(w));
    }
    __syncthreads();

    const int wave = threadIdx.x >> 6;
    const int lane = threadIdx.x & 63;
    const int g    = lane >> 3;                  // K-group 0..7
    const int sub  = lane & 7;                   // 8 B slice of the 64 B row
    const int row  = base + wave;

    float acc[8] = {0.f, 0.f, 0.f, 0.f, 0.f, 0.f, 0.f, 0.f};
    #pragma unroll
    for (int i = 0; i < ITERS; ++i) {
        const uint2 e  = nw[wave][i * GROUPS + g];
        const float wk = __uint_as_float(e.y);
        const uint2 v  = *(const uint2*)(emb8 + (size_t)e.x * (D / 4) + sub * 2);
        acc[0] += wk * sb(v.x, 0);
        acc[1] += wk * sb(v.x, 1);
        acc[2] += wk * sb(v.x, 2);
        acc[3] += wk * sb(v.x, 3);
        acc[4] += wk * sb(v.y, 0);
        acc[5] += wk * sb(v.y, 1);
        acc[6] += wk * sb(v.y, 2);
        acc[7] += wk * sb(v.y, 3);
    }

    // Reduce the 8 K-groups (lanes sub, 8+sub, ..., 56+sub hold partials).
    #pragma unroll
    for (int off = 8; off <= 32; off <<= 1) {
        #pragma unroll
        for (int j = 0; j < 8; ++j) acc[j] += __shfl_xor(acc[j], off);
    }

    if (row < batch && g == 0) {
        float* o = out + (size_t)row * D + sub * 8;
        *(float4*)(o)     = make_float4(acc[0], acc[1], acc[2], acc[3]);
        *(float4*)(o + 4) = make_float4(acc[4], acc[5], acc[6], acc[7]);
    }
}

// ---------- fallback (fp32 path) if workspace is too small
__global__ __launch_bounds__(THREADS)
void social_agg_f32(const int* __restrict__ nodes,
                    const int* __restrict__ u_u,
                    const float* __restrict__ u_u_l,
                    const float* __restrict__ emb,
                    float* __restrict__ out,
                    int batch)
{
    __shared__ uint2 nw[ROWS_PER_BLOCK][KPAD];
    const int base = blockIdx.x * ROWS_PER_BLOCK;
    const int p = threadIdx.x;
    if (p < ROWS_PER_BLOCK * KPAD) {
        const int r = p / KPAD, k = p - r * KPAD, row = base + r;
        int nb = 0; float w = 0.0f;
        if (row < batch && k < K) {
            const int node = nodes[row];
            const float Na = u_u_l[node];
            nb = u_u[node * K + k];
            const float prod = Na * u_u_l[nb];
            w = (prod > 0.0f) ? rsqrtf(prod) : 0.0f;
        }
        nw[r][k] = make_uint2((unsigned)nb, __float_as_uint(w));
    }
    __syncthreads();
    const int wave = threadIdx.x >> 6, lane = threadIdx.x & 63;
    const int kk = lane >> 4, sub = lane & 15, row = base + wave;
    float4 acc = make_float4(0.f, 0.f, 0.f, 0.f);
    #pragma unroll
    for (int i = 0; i < 13; ++i) {
        const int k = i * 4 + kk;
        const uint2 e = nw[wave][k < KPAD ? k : 0];
        const float wk = (k < KPAD) ? __uint_as_float(e.y) : 0.0f;
        const float4 v = *(const float4*)(emb + (size_t)e.x * D + sub * 4);
        acc.x += wk * v.x; acc.y += wk * v.y; acc.z += wk * v.z; acc.w += wk * v.w;
    }
    #pragma unroll
    for (int off = 16; off <= 32; off <<= 1) {
        acc.x += __shfl_xor(acc.x, off);
        acc.y += __shfl_xor(acc.y, off);
        acc.z += __shfl_xor(acc.z, off);
        acc.w += __shfl_xor(acc.w, off);
    }
    if (row < batch && kk == 0)
        *(float4*)(out + (size_t)row * D + sub * 4) = acc;
}

extern "C" void kernel_launch(void* const* d_in, const int* in_sizes, int n_in,
                              void* d_out, int out_size, void* d_ws, size_t ws_size,
                              hipStream_t stream) {
    const int*   nodes = (const int*)d_in[0];
    const int*   u_u   = (const int*)d_in[1];
    const float* u_u_l = (const float*)d_in[2];
    const float* emb   = (const float*)d_in[3];
    float*       out   = (float*)d_out;

    const int batch  = in_sizes[0];
    const int nuser  = in_sizes[1] / K;                  // N_USERS
    const int blocks = (batch + ROWS_PER_BLOCK - 1) / ROWS_PER_BLOCK;

    const size_t emb8_bytes  = (size_t)nuser * D;        // int8 table (64 B/row)
    const size_t scale_bytes = (size_t)nuser * 4;
    const size_t rtab_bytes  = (size_t)nuser * 4;
    if (ws_size >= emb8_bytes + scale_bytes + rtab_bytes) {
        unsigned* emb8  = (unsigned*)d_ws;
        float*    scale = (float*)((char*)d_ws + emb8_bytes);
        float*    rtab  = (float*)((char*)d_ws + emb8_bytes + scale_bytes);
        const int pthreads = nuser * 16;                 // 16 lanes per row
        const int pblocks  = (pthreads + THREADS - 1) / THREADS;
        prep_q8<<<pblocks, THREADS, 0, stream>>>(emb, u_u_l, emb8, scale, rtab, nuser);
        social_agg_q8<<<blocks, THREADS, 0, stream>>>(nodes, u_u, rtab, scale, emb8,
                                                      out, batch);
    } else {
        social_agg_f32<<<blocks, THREADS, 0, stream>>>(nodes, u_u, u_u_l, emb,
                                                       out, batch);
    }
}

// Round 7
// 29.235 us; speedup vs baseline: 1.0150x; 1.0097x over previous
//
#include <hip/hip_runtime.h>

#define D 64
#define K 50
#define GROUPS 8              // 8 groups x 8 lanes; each group reads one neighbor row/iter
#define KPAD 56               // ceil(50/8)*8
#define ITERS (KPAD / GROUPS) // 7
#define RPB 8                 // rows per block; each of 4 waves reduces 2 rows
#define THREADS 256

// ---------- prologue: per-row int8 quant of emb; rtab[u]=rsqrt(deg); wtab[u]=rtab[u]*scale[u]
__global__ __launch_bounds__(THREADS)
void prep_q8(const float* __restrict__ emb, const float* __restrict__ deg,
             unsigned* __restrict__ emb8, float* __restrict__ rtab,
             float* __restrict__ wtab, int nuser)
{
    const int tid = blockIdx.x * THREADS + threadIdx.x;
    const int row = tid >> 4;
    const int sub = tid & 15;
    if (row >= nuser) return;

    const float4 f = ((const float4*)emb)[row * 16 + sub];
    float m = fmaxf(fmaxf(fabsf(f.x), fabsf(f.y)), fmaxf(fabsf(f.z), fabsf(f.w)));
    #pragma unroll
    for (int off = 1; off < 16; off <<= 1)
        m = fmaxf(m, __shfl_xor(m, off));            // rowmax within the 16-lane group
    const float inv = (m > 0.0f) ? 127.0f / m : 0.0f;
    const int q0 = (int)rintf(f.x * inv);
    const int q1 = (int)rintf(f.y * inv);
    const int q2 = (int)rintf(f.z * inv);
    const int q3 = (int)rintf(f.w * inv);
    const unsigned pk = (q0 & 0xFF) | ((q1 & 0xFF) << 8) |
                        ((q2 & 0xFF) << 16) | ((unsigned)(q3 & 0xFF) << 24);
    emb8[row * 16 + sub] = pk;
    if (sub == 0) {
        const float n = deg[row];
        const float r = (n > 0.0f) ? rsqrtf(n) : 0.0f;
        rtab[row] = r;
        wtab[row] = r * m * (1.0f / 127.0f);         // rsqrt(deg)*scale folded into ONE table
    }
}

__device__ __forceinline__ float sb(unsigned v, int byte) {
    return (float)((int)(v << (24 - 8 * byte)) >> 24);   // sign-extend byte -> float
}

// ---------- main: int8 gather; 8 lanes x 8 B per 64 B row; each wave reduces 2 rows
__global__ __launch_bounds__(THREADS)
void social_agg_q8(const int* __restrict__ nodes,
                   const int* __restrict__ u_u,
                   const float* __restrict__ rtab,
                   const float* __restrict__ wtab,
                   const unsigned* __restrict__ emb8,
                   float* __restrict__ out,
                   int batch)
{
    __shared__ uint2 nw[RPB][KPAD];              // x = neighbor id, y = bitcast(w)
    const int base = blockIdx.x * RPB;

    // Phase 1: one random wtab gather per (row,k); 448 slots over 256 threads.
    for (int p = threadIdx.x; p < RPB * KPAD; p += THREADS) {
        const int r   = p / KPAD;
        const int k   = p - r * KPAD;
        const int row = base + r;
        int nb = 0; float w = 0.0f;
        if (row < batch && k < K) {
            const int node = nodes[row];
            nb = u_u[node * K + k];
            w  = rtab[node] * wtab[nb];          // weight * dequant scale, 0 if deg==0
        }
        nw[r][k] = make_uint2((unsigned)nb, __float_as_uint(w));
    }
    __syncthreads();

    const int wave = threadIdx.x >> 6;
    const int lane = threadIdx.x & 63;
    const int g    = lane >> 3;                  // K-group 0..7
    const int sub  = lane & 7;                   // 8 B slice of the 64 B row
    const int r0   = wave * 2;                   // this wave's two rows
    const int row0 = base + r0;

    float a0[8] = {0,0,0,0,0,0,0,0};
    float a1[8] = {0,0,0,0,0,0,0,0};
    #pragma unroll
    for (int i = 0; i < ITERS; ++i) {
        const uint2 e0 = nw[r0][i * GROUPS + g];
        const uint2 e1 = nw[r0 + 1][i * GROUPS + g];
        const float w0 = __uint_as_float(e0.y);
        const float w1 = __uint_as_float(e1.y);
        const uint2 v0 = *(const uint2*)(emb8 + (size_t)e0.x * (D / 4) + sub * 2);
        const uint2 v1 = *(const uint2*)(emb8 + (size_t)e1.x * (D / 4) + sub * 2);
        a0[0] += w0 * sb(v0.x, 0); a0[1] += w0 * sb(v0.x, 1);
        a0[2] += w0 * sb(v0.x, 2); a0[3] += w0 * sb(v0.x, 3);
        a0[4] += w0 * sb(v0.y, 0); a0[5] += w0 * sb(v0.y, 1);
        a0[6] += w0 * sb(v0.y, 2); a0[7] += w0 * sb(v0.y, 3);
        a1[0] += w1 * sb(v1.x, 0); a1[1] += w1 * sb(v1.x, 1);
        a1[2] += w1 * sb(v1.x, 2); a1[3] += w1 * sb(v1.x, 3);
        a1[4] += w1 * sb(v1.y, 0); a1[5] += w1 * sb(v1.y, 1);
        a1[6] += w1 * sb(v1.y, 2); a1[7] += w1 * sb(v1.y, 3);
    }

    #pragma unroll
    for (int off = 8; off <= 32; off <<= 1) {
        #pragma unroll
        for (int j = 0; j < 8; ++j) { a0[j] += __shfl_xor(a0[j], off);
                                      a1[j] += __shfl_xor(a1[j], off); }
    }

    if (g == 0) {
        if (row0 < batch) {
            float* o = out + (size_t)row0 * D + sub * 8;
            *(float4*)(o)     = make_float4(a0[0], a0[1], a0[2], a0[3]);
            *(float4*)(o + 4) = make_float4(a0[4], a0[5], a0[6], a0[7]);
        }
        if (row0 + 1 < batch) {
            float* o = out + (size_t)(row0 + 1) * D + sub * 8;
            *(float4*)(o)     = make_float4(a1[0], a1[1], a1[2], a1[3]);
            *(float4*)(o + 4) = make_float4(a1[4], a1[5], a1[6], a1[7]);
        }
    }
}

// ---------- fallback (fp32 path) if workspace is too small
__global__ __launch_bounds__(THREADS)
void social_agg_f32(const int* __restrict__ nodes,
                    const int* __restrict__ u_u,
                    const float* __restrict__ u_u_l,
                    const float* __restrict__ emb,
                    float* __restrict__ out,
                    int batch)
{
    __shared__ uint2 nw[4][52];
    const int base = blockIdx.x * 4;
    const int p = threadIdx.x;
    if (p < 4 * 52) {
        const int r = p / 52, k = p - r * 52, row = base + r;
        int nb = 0; float w = 0.0f;
        if (row < batch && k < K) {
            const int node = nodes[row];
            const float Na = u_u_l[node];
            nb = u_u[node * K + k];
            const float prod = Na * u_u_l[nb];
            w = (prod > 0.0f) ? rsqrtf(prod) : 0.0f;
        }
        nw[r][k] = make_uint2((unsigned)nb, __float_as_uint(w));
    }
    __syncthreads();
    const int wave = threadIdx.x >> 6, lane = threadIdx.x & 63;
    const int kk = lane >> 4, sub = lane & 15, row = base + wave;
    float4 acc = make_float4(0.f, 0.f, 0.f, 0.f);
    #pragma unroll
    for (int i = 0; i < 13; ++i) {
        const uint2 e = nw[wave][i * 4 + kk];
        const float wk = __uint_as_float(e.y);
        const float4 v = *(const float4*)(emb + (size_t)e.x * D + sub * 4);
        acc.x += wk * v.x; acc.y += wk * v.y; acc.z += wk * v.z; acc.w += wk * v.w;
    }
    #pragma unroll
    for (int off = 16; off <= 32; off <<= 1) {
        acc.x += __shfl_xor(acc.x, off);
        acc.y += __shfl_xor(acc.y, off);
        acc.z += __shfl_xor(acc.z, off);
        acc.w += __shfl_xor(acc.w, off);
    }
    if (row < batch && kk == 0)
        *(float4*)(out + (size_t)row * D + sub * 4) = acc;
}

extern "C" void kernel_launch(void* const* d_in, const int* in_sizes, int n_in,
                              void* d_out, int out_size, void* d_ws, size_t ws_size,
                              hipStream_t stream) {
    const int*   nodes = (const int*)d_in[0];
    const int*   u_u   = (const int*)d_in[1];
    const float* u_u_l = (const float*)d_in[2];
    const float* emb   = (const float*)d_in[3];
    float*       out   = (float*)d_out;

    const int batch = in_sizes[0];
    const int nuser = in_sizes[1] / K;                   // N_USERS

    const size_t emb8_bytes = (size_t)nuser * D;         // int8 table (64 B/row)
    const size_t tab_bytes  = (size_t)nuser * 4;
    if (ws_size >= emb8_bytes + 2 * tab_bytes) {
        unsigned* emb8 = (unsigned*)d_ws;
        float*    rtab = (float*)((char*)d_ws + emb8_bytes);
        float*    wtab = (float*)((char*)d_ws + emb8_bytes + tab_bytes);
        const int pthreads = nuser * 16;
        const int pblocks  = (pthreads + THREADS - 1) / THREADS;
        prep_q8<<<pblocks, THREADS, 0, stream>>>(emb, u_u_l, emb8, rtab, wtab, nuser);
        const int blocks = (batch + RPB - 1) / RPB;
        social_agg_q8<<<blocks, THREADS, 0, stream>>>(nodes, u_u, rtab, wtab, emb8,
                                                      out, batch);
    } else {
        const int blocks = (batch + 3) / 4;
        social_agg_f32<<<blocks, THREADS, 0, stream>>>(nodes, u_u, u_u_l, emb,
                                                       out, batch);
    }
}